// Round 11
// baseline (150.543 us; speedup 1.0000x reference)
//
#include <hip/hip_runtime.h>
#include <hip/hip_bf16.h>
#include <math.h>

#define NN 512

// smearing constants
#define START 0.006737946999085467f            // exp(-5)
#define STEP  ((1.0f - START) * (1.0f/15.0f))  // linspace step
#define SB    (0.125f * (1.0f - START))
#define BETA  (1.0f/(SB*SB))
#define LOG2E 1.4426950408889634f
#define NB    (-(BETA)*LOG2E)                  // exp(-beta t^2) = exp2(NB t^2)

// ===========================================================================
// R11 = R10 + c-PAIR contract (the a-kernels were LDS-issue-bound: 5 b128
// LDS reads per 38 FMAs; each G read now feeds 2 c-columns -> LDS instr
// count halves). 256 thr = 8 cpairs x 32 j-slots, 2 j-tiles of 32.
// Register discipline kept: no launch-bounds min-wave hint, t-loop unroll 1
// (one tile's 16 float4 in flight), fp32 G.
// Kept: k0 W-transpose, transposed att2t, un-hinted allocator.
// ===========================================================================

__global__ __launch_bounds__(256) void k0(const float* __restrict__ W,
                                          float* __restrict__ Wt)
{
    __shared__ float ldsb[256];
    const int row = blockIdx.x;                // (a,j) 0..1023
    ldsb[threadIdx.x] = W[(size_t)row*256 + threadIdx.x];
    __syncthreads();
    const int c = threadIdx.x >> 4, r = threadIdx.x & 15;
    Wt[(size_t)row*256 + threadIdx.x] = ldsb[r*16 + c];   // Wt[row][c][r]
}

// ---------------------------------------------------------------------------
// k1a: stage-1 partials. part1[i][jc][96], 96 = kq*48 + b*16 + c.
// ---------------------------------------------------------------------------
__global__ __launch_bounds__(256) void k1a(const float* __restrict__ x,
                                           const float* __restrict__ Wt,
                                           float* __restrict__ part1)
{
    const int ib = blockIdx.x & 127, jc = blockIdx.x >> 7;
    const int i0 = ib * 4;
    const int tid = threadIdx.x;
    const int cp = tid & 7, js = tid >> 3;     // 8 c-pairs x 32 j-slots
    const int lane = tid & 63, wv = tid >> 6;

    __shared__ float  lG[4][64][16];           // fp32 G
    __shared__ float4 lP[4][64];
    __shared__ float  s_part[4][8][50];        // [wave][cp][48+pad]

    // ---- phase 1: G + d for all (4 i) x (64 j), one (i,j) per thread ----
    {
        const int pi = tid >> 6, pj = tid & 63;
        const int jg = jc*64 + pj;
        const float xi0 = x[(i0+pi)*3+0], xi1 = x[(i0+pi)*3+1], xi2 = x[(i0+pi)*3+2];
        float d0 = xi0 - x[jg*3+0];
        float d1 = xi1 - x[jg*3+1];
        float d2 = xi2 - x[jg*3+2];
        float nsq = fmaf(d0,d0, fmaf(d1,d1, fmaf(d2,d2, 1e-6f)));
        float rs  = __builtin_amdgcn_rsqf(nsq);
        float nrm = nsq * rs;
        float inv = rs * rs;
        float cutv = 0.f;
        if (nrm < 5.0f) cutv = 0.5f*(__cosf(nrm*0.6283185307179586f)+1.0f);
        float en = exp2f(-LOG2E * nrm);
        lP[pi][pj] = make_float4(d0*inv, d1*inv, d2*inv, 0.f);
        float4* dst = reinterpret_cast<float4*>(&lG[pi][pj][0]);
        #pragma unroll
        for (int rq = 0; rq < 4; ++rq) {
            float t0 = en - (START + STEP*(float)(4*rq+0));
            float t1 = en - (START + STEP*(float)(4*rq+1));
            float t2 = en - (START + STEP*(float)(4*rq+2));
            float t3 = en - (START + STEP*(float)(4*rq+3));
            dst[rq] = make_float4(cutv*exp2f(NB*t0*t0), cutv*exp2f(NB*t1*t1),
                                  cutv*exp2f(NB*t2*t2), cutv*exp2f(NB*t3*t3));
        }
    }
    __syncthreads();                            // the ONLY main-loop barrier

    float acc[48];                              // e*24 + i*6 + kq*3 + b
    #pragma unroll
    for (int v = 0; v < 48; ++v) acc[v] = 0.f;

    #pragma unroll 1
    for (int t = 0; t < 2; ++t) {
        const int jl = js + 32*t;
        const int jg = jc*64 + jl;
        // c0 = 2cp, c1 = 2cp+1: 32 contiguous floats per kq
        const float4* Kp = reinterpret_cast<const float4*>(Wt + (size_t)jg*256 + cp*32);
        const float4* Qp = reinterpret_cast<const float4*>(Wt + (size_t)NN*256 + (size_t)jg*256 + cp*32);
        float4 kA0 = Kp[0], kA1 = Kp[1], kA2 = Kp[2], kA3 = Kp[3];   // c0
        float4 kB0 = Kp[4], kB1 = Kp[5], kB2 = Kp[6], kB3 = Kp[7];   // c1
        float4 qA0 = Qp[0], qA1 = Qp[1], qA2 = Qp[2], qA3 = Qp[3];
        float4 qB0 = Qp[4], qB1 = Qp[5], qB2 = Qp[6], qB3 = Qp[7];

        #pragma unroll
        for (int i = 0; i < 4; ++i) {
            const float4* gp = reinterpret_cast<const float4*>(&lG[i][jl][0]);
            float4 g0 = gp[0], g1 = gp[1], g2 = gp[2], g3 = gp[3];
            float tk0, tq0, tk1, tq1;
            tk0 = g0.x*kA0.x; tq0 = g0.x*qA0.x; tk1 = g0.x*kB0.x; tq1 = g0.x*qB0.x;
            tk0 = fmaf(g0.y,kA0.y,tk0); tq0 = fmaf(g0.y,qA0.y,tq0); tk1 = fmaf(g0.y,kB0.y,tk1); tq1 = fmaf(g0.y,qB0.y,tq1);
            tk0 = fmaf(g0.z,kA0.z,tk0); tq0 = fmaf(g0.z,qA0.z,tq0); tk1 = fmaf(g0.z,kB0.z,tk1); tq1 = fmaf(g0.z,qB0.z,tq1);
            tk0 = fmaf(g0.w,kA0.w,tk0); tq0 = fmaf(g0.w,qA0.w,tq0); tk1 = fmaf(g0.w,kB0.w,tk1); tq1 = fmaf(g0.w,qB0.w,tq1);
            tk0 = fmaf(g1.x,kA1.x,tk0); tq0 = fmaf(g1.x,qA1.x,tq0); tk1 = fmaf(g1.x,kB1.x,tk1); tq1 = fmaf(g1.x,qB1.x,tq1);
            tk0 = fmaf(g1.y,kA1.y,tk0); tq0 = fmaf(g1.y,qA1.y,tq0); tk1 = fmaf(g1.y,kB1.y,tk1); tq1 = fmaf(g1.y,qB1.y,tq1);
            tk0 = fmaf(g1.z,kA1.z,tk0); tq0 = fmaf(g1.z,qA1.z,tq0); tk1 = fmaf(g1.z,kB1.z,tk1); tq1 = fmaf(g1.z,qB1.z,tq1);
            tk0 = fmaf(g1.w,kA1.w,tk0); tq0 = fmaf(g1.w,qA1.w,tq0); tk1 = fmaf(g1.w,kB1.w,tk1); tq1 = fmaf(g1.w,qB1.w,tq1);
            tk0 = fmaf(g2.x,kA2.x,tk0); tq0 = fmaf(g2.x,qA2.x,tq0); tk1 = fmaf(g2.x,kB2.x,tk1); tq1 = fmaf(g2.x,qB2.x,tq1);
            tk0 = fmaf(g2.y,kA2.y,tk0); tq0 = fmaf(g2.y,qA2.y,tq0); tk1 = fmaf(g2.y,kB2.y,tk1); tq1 = fmaf(g2.y,qB2.y,tq1);
            tk0 = fmaf(g2.z,kA2.z,tk0); tq0 = fmaf(g2.z,qA2.z,tq0); tk1 = fmaf(g2.z,kB2.z,tk1); tq1 = fmaf(g2.z,qB2.z,tq1);
            tk0 = fmaf(g2.w,kA2.w,tk0); tq0 = fmaf(g2.w,qA2.w,tq0); tk1 = fmaf(g2.w,kB2.w,tk1); tq1 = fmaf(g2.w,qB2.w,tq1);
            tk0 = fmaf(g3.x,kA3.x,tk0); tq0 = fmaf(g3.x,qA3.x,tq0); tk1 = fmaf(g3.x,kB3.x,tk1); tq1 = fmaf(g3.x,qB3.x,tq1);
            tk0 = fmaf(g3.y,kA3.y,tk0); tq0 = fmaf(g3.y,qA3.y,tq0); tk1 = fmaf(g3.y,kB3.y,tk1); tq1 = fmaf(g3.y,qB3.y,tq1);
            tk0 = fmaf(g3.z,kA3.z,tk0); tq0 = fmaf(g3.z,qA3.z,tq0); tk1 = fmaf(g3.z,kB3.z,tk1); tq1 = fmaf(g3.z,qB3.z,tq1);
            tk0 = fmaf(g3.w,kA3.w,tk0); tq0 = fmaf(g3.w,qA3.w,tq0); tk1 = fmaf(g3.w,kB3.w,tk1); tq1 = fmaf(g3.w,qB3.w,tq1);
            float4 dd = lP[i][jl];
            acc[     i*6+0] = fmaf(tk0, dd.x, acc[     i*6+0]);
            acc[     i*6+1] = fmaf(tk0, dd.y, acc[     i*6+1]);
            acc[     i*6+2] = fmaf(tk0, dd.z, acc[     i*6+2]);
            acc[     i*6+3] = fmaf(tq0, dd.x, acc[     i*6+3]);
            acc[     i*6+4] = fmaf(tq0, dd.y, acc[     i*6+4]);
            acc[     i*6+5] = fmaf(tq0, dd.z, acc[     i*6+5]);
            acc[24 + i*6+0] = fmaf(tk1, dd.x, acc[24 + i*6+0]);
            acc[24 + i*6+1] = fmaf(tk1, dd.y, acc[24 + i*6+1]);
            acc[24 + i*6+2] = fmaf(tk1, dd.z, acc[24 + i*6+2]);
            acc[24 + i*6+3] = fmaf(tq1, dd.x, acc[24 + i*6+3]);
            acc[24 + i*6+4] = fmaf(tq1, dd.y, acc[24 + i*6+4]);
            acc[24 + i*6+5] = fmaf(tq1, dd.z, acc[24 + i*6+5]);
        }
    }

    // reduce over 32 js: lane bits 3,4,5 then cross-wave (js = wv*8 + lane>>3)
    #pragma unroll
    for (int v = 0; v < 48; ++v) {
        float t = acc[v];
        t += __shfl_xor(t, 8);
        t += __shfl_xor(t, 16);
        t += __shfl_xor(t, 32);
        if (lane < 8) s_part[wv][cp][v] = t;
    }
    __syncthreads();

    for (int v = tid; v < 384; v += 256) {
        int i = v / 96, o = v - i*96;
        int kq = o / 48, rem = o - kq*48;
        int b = rem >> 4, c2 = rem & 15;
        int cp2 = c2 >> 1, e = c2 & 1;
        int f = e*24 + i*6 + kq*3 + b;
        float sum = s_part[0][cp2][f] + s_part[1][cp2][f]
                  + s_part[2][cp2][f] + s_part[3][cp2][f];
        part1[(i0+i)*768 + jc*96 + o] = sum;
    }
}

// ---------------------------------------------------------------------------
// k1b: reduce 8 partials -> att1 -> silu(W1) -> att2 row (TRANSPOSED store).
// att2t[i][q2][c][r] = att2[i][q2*256 + r*16 + c]
// ---------------------------------------------------------------------------
__global__ __launch_bounds__(256) void k1b(const float* __restrict__ part1,
                                           const float* __restrict__ W1,
                                           const float* __restrict__ b1,
                                           const float* __restrict__ W2,
                                           float* __restrict__ att2t)
{
    const int i = blockIdx.x;
    const int tid = threadIdx.x;
    __shared__ float s_bkq[96];
    __shared__ float s_att[256];
    __shared__ float s_z[16][16];
    __shared__ float s_a1[16];

    if (tid < 96) {
        const float* p = part1 + i*768 + tid;
        float s = 0.f;
        #pragma unroll
        for (int k = 0; k < 8; ++k) s += p[k*96];
        s_bkq[tid] = s;
    }
    __syncthreads();

    {
        int h = tid >> 4, g = tid & 15;
        s_att[tid] = s_bkq[     h]*s_bkq[48+     g]
                   + s_bkq[16 + h]*s_bkq[48+16 + g]
                   + s_bkq[32 + h]*s_bkq[48+32 + g];
    }
    __syncthreads();

    {
        int h = tid & 15, seg = tid >> 4;
        const float* w1 = W1 + h*256 + seg*16;
        const float* a  = s_att + seg*16;
        float p = 0.f;
        #pragma unroll
        for (int k = 0; k < 16; ++k) p = fmaf(a[k], w1[k], p);
        s_z[seg][h] = p;
    }
    __syncthreads();

    if (tid < 16) {
        float z = b1[tid];
        #pragma unroll
        for (int seg = 0; seg < 16; ++seg) z += s_z[seg][tid];
        s_a1[tid] = z / (1.0f + __expf(-z));
    }
    __syncthreads();

    float a1[16];
    #pragma unroll
    for (int cc = 0; cc < 16; ++cc) a1[cc] = s_a1[cc];
    #pragma unroll
    for (int p = 0; p < 4; ++p) {
        int o = tid + p*256;
        const float4* w2 = reinterpret_cast<const float4*>(W2 + o*16);
        float4 wa = w2[0], wb = w2[1], wc = w2[2], wd = w2[3];
        float accv = wa.x*a1[0] + wa.y*a1[1] + wa.z*a1[2] + wa.w*a1[3]
                   + wb.x*a1[4] + wb.y*a1[5] + wb.z*a1[6] + wb.w*a1[7]
                   + wc.x*a1[8] + wc.y*a1[9] + wc.z*a1[10]+ wc.w*a1[11]
                   + wd.x*a1[12]+ wd.y*a1[13]+ wd.z*a1[14]+ wd.w*a1[15];
        // transposed store: q2 = o>>8, r = (o>>4)&15, c = o&15
        att2t[i*1024 + ((o>>8)*256) + ((o&15)*16) + ((o>>4)&15)] = accv;
    }
}

// ---------------------------------------------------------------------------
// k2a: stage-3 right-term + S partials, c-pair contract. part2[i][jc][144].
// ---------------------------------------------------------------------------
__global__ __launch_bounds__(256) void k2a(const float* __restrict__ x,
                                           const float* __restrict__ att2t,
                                           float* __restrict__ part2)
{
    const int ib = blockIdx.x & 127, jc = blockIdx.x >> 7;
    const int i0 = ib * 4;
    const int tid = threadIdx.x;
    const int cp = tid & 7, js = tid >> 3;
    const int lane = tid & 63, wv = tid >> 6;

    __shared__ float  lG[4][64][16];
    __shared__ float4 lP[4][64];
    __shared__ float  s_part[4][8][74];        // [wave][cp][72+pad]

    {
        const int pi = tid >> 6, pj = tid & 63;
        const int jg = jc*64 + pj;
        const float xi0 = x[(i0+pi)*3+0], xi1 = x[(i0+pi)*3+1], xi2 = x[(i0+pi)*3+2];
        float d0 = xi0 - x[jg*3+0];
        float d1 = xi1 - x[jg*3+1];
        float d2 = xi2 - x[jg*3+2];
        float nsq = fmaf(d0,d0, fmaf(d1,d1, fmaf(d2,d2, 1e-6f)));
        float rs  = __builtin_amdgcn_rsqf(nsq);
        float nrm = nsq * rs;
        float inv = rs * rs;
        float cutv = 0.f;
        if (nrm < 5.0f) cutv = 0.5f*(__cosf(nrm*0.6283185307179586f)+1.0f);
        float en = exp2f(-LOG2E * nrm);
        lP[pi][pj] = make_float4(d0*inv, d1*inv, d2*inv, 0.f);
        float4* dst = reinterpret_cast<float4*>(&lG[pi][pj][0]);
        #pragma unroll
        for (int rq = 0; rq < 4; ++rq) {
            float t0 = en - (START + STEP*(float)(4*rq+0));
            float t1 = en - (START + STEP*(float)(4*rq+1));
            float t2 = en - (START + STEP*(float)(4*rq+2));
            float t3 = en - (START + STEP*(float)(4*rq+3));
            dst[rq] = make_float4(cutv*exp2f(NB*t0*t0), cutv*exp2f(NB*t1*t1),
                                  cutv*exp2f(NB*t2*t2), cutv*exp2f(NB*t3*t3));
        }
    }
    __syncthreads();

    float acc[72];       // 48 main (e*24+i*6+kq*3+b) + 24 S (48+e*12+i*3+b, r=2cp+e)
    #pragma unroll
    for (int v = 0; v < 72; ++v) acc[v] = 0.f;

    #pragma unroll 1
    for (int t = 0; t < 2; ++t) {
        const int jl = js + 32*t;
        const int jg = jc*64 + jl;
        const float4* Kp = reinterpret_cast<const float4*>(att2t + (size_t)jg*1024 + 512 + cp*32);
        const float4* Qp = reinterpret_cast<const float4*>(att2t + (size_t)jg*1024 + 768 + cp*32);
        float4 kA0 = Kp[0], kA1 = Kp[1], kA2 = Kp[2], kA3 = Kp[3];
        float4 kB0 = Kp[4], kB1 = Kp[5], kB2 = Kp[6], kB3 = Kp[7];
        float4 qA0 = Qp[0], qA1 = Qp[1], qA2 = Qp[2], qA3 = Qp[3];
        float4 qB0 = Qp[4], qB1 = Qp[5], qB2 = Qp[6], qB3 = Qp[7];

        #pragma unroll
        for (int i = 0; i < 4; ++i) {
            const float4* gp = reinterpret_cast<const float4*>(&lG[i][jl][0]);
            float4 g0 = gp[0], g1 = gp[1], g2 = gp[2], g3 = gp[3];
            float tk0, tq0, tk1, tq1;
            tk0 = g0.x*kA0.x; tq0 = g0.x*qA0.x; tk1 = g0.x*kB0.x; tq1 = g0.x*qB0.x;
            tk0 = fmaf(g0.y,kA0.y,tk0); tq0 = fmaf(g0.y,qA0.y,tq0); tk1 = fmaf(g0.y,kB0.y,tk1); tq1 = fmaf(g0.y,qB0.y,tq1);
            tk0 = fmaf(g0.z,kA0.z,tk0); tq0 = fmaf(g0.z,qA0.z,tq0); tk1 = fmaf(g0.z,kB0.z,tk1); tq1 = fmaf(g0.z,qB0.z,tq1);
            tk0 = fmaf(g0.w,kA0.w,tk0); tq0 = fmaf(g0.w,qA0.w,tq0); tk1 = fmaf(g0.w,kB0.w,tk1); tq1 = fmaf(g0.w,qB0.w,tq1);
            tk0 = fmaf(g1.x,kA1.x,tk0); tq0 = fmaf(g1.x,qA1.x,tq0); tk1 = fmaf(g1.x,kB1.x,tk1); tq1 = fmaf(g1.x,qB1.x,tq1);
            tk0 = fmaf(g1.y,kA1.y,tk0); tq0 = fmaf(g1.y,qA1.y,tq0); tk1 = fmaf(g1.y,kB1.y,tk1); tq1 = fmaf(g1.y,qB1.y,tq1);
            tk0 = fmaf(g1.z,kA1.z,tk0); tq0 = fmaf(g1.z,qA1.z,tq0); tk1 = fmaf(g1.z,kB1.z,tk1); tq1 = fmaf(g1.z,qB1.z,tq1);
            tk0 = fmaf(g1.w,kA1.w,tk0); tq0 = fmaf(g1.w,qA1.w,tq0); tk1 = fmaf(g1.w,kB1.w,tk1); tq1 = fmaf(g1.w,qB1.w,tq1);
            tk0 = fmaf(g2.x,kA2.x,tk0); tq0 = fmaf(g2.x,qA2.x,tq0); tk1 = fmaf(g2.x,kB2.x,tk1); tq1 = fmaf(g2.x,qB2.x,tq1);
            tk0 = fmaf(g2.y,kA2.y,tk0); tq0 = fmaf(g2.y,qA2.y,tq0); tk1 = fmaf(g2.y,kB2.y,tk1); tq1 = fmaf(g2.y,qB2.y,tq1);
            tk0 = fmaf(g2.z,kA2.z,tk0); tq0 = fmaf(g2.z,qA2.z,tq0); tk1 = fmaf(g2.z,kB2.z,tk1); tq1 = fmaf(g2.z,qB2.z,tq1);
            tk0 = fmaf(g2.w,kA2.w,tk0); tq0 = fmaf(g2.w,qA2.w,tq0); tk1 = fmaf(g2.w,kB2.w,tk1); tq1 = fmaf(g2.w,qB2.w,tq1);
            tk0 = fmaf(g3.x,kA3.x,tk0); tq0 = fmaf(g3.x,qA3.x,tq0); tk1 = fmaf(g3.x,kB3.x,tk1); tq1 = fmaf(g3.x,qB3.x,tq1);
            tk0 = fmaf(g3.y,kA3.y,tk0); tq0 = fmaf(g3.y,qA3.y,tq0); tk1 = fmaf(g3.y,kB3.y,tk1); tq1 = fmaf(g3.y,qB3.y,tq1);
            tk0 = fmaf(g3.z,kA3.z,tk0); tq0 = fmaf(g3.z,qA3.z,tq0); tk1 = fmaf(g3.z,kB3.z,tk1); tq1 = fmaf(g3.z,qB3.z,tq1);
            tk0 = fmaf(g3.w,kA3.w,tk0); tq0 = fmaf(g3.w,qA3.w,tq0); tk1 = fmaf(g3.w,kB3.w,tk1); tq1 = fmaf(g3.w,qB3.w,tq1);
            float4 dd = lP[i][jl];
            acc[     i*6+0] = fmaf(tk0, dd.x, acc[     i*6+0]);
            acc[     i*6+1] = fmaf(tk0, dd.y, acc[     i*6+1]);
            acc[     i*6+2] = fmaf(tk0, dd.z, acc[     i*6+2]);
            acc[     i*6+3] = fmaf(tq0, dd.x, acc[     i*6+3]);
            acc[     i*6+4] = fmaf(tq0, dd.y, acc[     i*6+4]);
            acc[     i*6+5] = fmaf(tq0, dd.z, acc[     i*6+5]);
            acc[24 + i*6+0] = fmaf(tk1, dd.x, acc[24 + i*6+0]);
            acc[24 + i*6+1] = fmaf(tk1, dd.y, acc[24 + i*6+1]);
            acc[24 + i*6+2] = fmaf(tk1, dd.z, acc[24 + i*6+2]);
            acc[24 + i*6+3] = fmaf(tq1, dd.x, acc[24 + i*6+3]);
            acc[24 + i*6+4] = fmaf(tq1, dd.y, acc[24 + i*6+4]);
            acc[24 + i*6+5] = fmaf(tq1, dd.z, acc[24 + i*6+5]);
            // S: this thread owns r = 2cp (e=0) and 2cp+1 (e=1)
            float2 gc = *reinterpret_cast<const float2*>(&lG[i][jl][2*cp]);
            acc[48 +      i*3+0] = fmaf(gc.x, dd.x, acc[48 +      i*3+0]);
            acc[48 +      i*3+1] = fmaf(gc.x, dd.y, acc[48 +      i*3+1]);
            acc[48 +      i*3+2] = fmaf(gc.x, dd.z, acc[48 +      i*3+2]);
            acc[48 + 12 + i*3+0] = fmaf(gc.y, dd.x, acc[48 + 12 + i*3+0]);
            acc[48 + 12 + i*3+1] = fmaf(gc.y, dd.y, acc[48 + 12 + i*3+1]);
            acc[48 + 12 + i*3+2] = fmaf(gc.y, dd.z, acc[48 + 12 + i*3+2]);
        }
    }

    #pragma unroll
    for (int v = 0; v < 72; ++v) {
        float t = acc[v];
        t += __shfl_xor(t, 8);
        t += __shfl_xor(t, 16);
        t += __shfl_xor(t, 32);
        if (lane < 8) s_part[wv][cp][v] = t;
    }
    __syncthreads();

    for (int v = tid; v < 576; v += 256) {
        int i = v / 144, o = v - i*144;
        int cp2, f;
        if (o < 96) {
            int kq = o / 48, rem = o - kq*48;
            int b = rem >> 4; int c2 = rem & 15;
            cp2 = c2 >> 1;
            f = (c2 & 1)*24 + i*6 + kq*3 + b;
        } else {
            int oS = o - 96;
            int r = oS / 3, b = oS - r*3;
            cp2 = r >> 1;
            f = 48 + (r & 1)*12 + i*3 + b;
        }
        float sum = s_part[0][cp2][f] + s_part[1][cp2][f]
                  + s_part[2][cp2][f] + s_part[3][cp2][f];
        part2[(i0+i)*1152 + jc*144 + o] = sum;
    }
}

// ---------------------------------------------------------------------------
// k2b: reduce 8 partials + left-term (transposed att2t rows) -> out. Grid 512.
// ---------------------------------------------------------------------------
__global__ __launch_bounds__(256) void k2b(const float* __restrict__ att2t,
                                           const float* __restrict__ part2,
                                           const float* __restrict__ W3,
                                           const float* __restrict__ b3,
                                           const float* __restrict__ W4,
                                           const float* __restrict__ b4,
                                           float* __restrict__ out)
{
    const int i = blockIdx.x;
    const int tid = threadIdx.x;
    __shared__ float s_red[144];
    __shared__ float s_att[256];
    __shared__ float s_z[16][16];
    __shared__ float s_a1[16];

    if (tid < 144) {
        const float* p = part2 + i*1152 + tid;
        float s = 0.f;
        #pragma unroll
        for (int k = 0; k < 8; ++k) s += p[k*144];
        s_red[tid] = s;
    }
    __syncthreads();

    if (tid < 96) {                      // left-term: bkq[c,b] += sum_r left[r,c]*S[r,b]
        int kq = tid / 48, rem = tid - kq*48;
        int b = rem >> 4, cc = rem & 15;
        const float4* lrow = reinterpret_cast<const float4*>(att2t + i*1024 + kq*256 + cc*16);
        float4 A = lrow[0], B = lrow[1], C = lrow[2], D = lrow[3];
        float add = 0.f;
        add = fmaf(A.x, s_red[96+ 0*3+b], add);
        add = fmaf(A.y, s_red[96+ 1*3+b], add);
        add = fmaf(A.z, s_red[96+ 2*3+b], add);
        add = fmaf(A.w, s_red[96+ 3*3+b], add);
        add = fmaf(B.x, s_red[96+ 4*3+b], add);
        add = fmaf(B.y, s_red[96+ 5*3+b], add);
        add = fmaf(B.z, s_red[96+ 6*3+b], add);
        add = fmaf(B.w, s_red[96+ 7*3+b], add);
        add = fmaf(C.x, s_red[96+ 8*3+b], add);
        add = fmaf(C.y, s_red[96+ 9*3+b], add);
        add = fmaf(C.z, s_red[96+10*3+b], add);
        add = fmaf(C.w, s_red[96+11*3+b], add);
        add = fmaf(D.x, s_red[96+12*3+b], add);
        add = fmaf(D.y, s_red[96+13*3+b], add);
        add = fmaf(D.z, s_red[96+14*3+b], add);
        add = fmaf(D.w, s_red[96+15*3+b], add);
        s_red[tid] += add;
    }
    __syncthreads();

    {
        int h = tid >> 4, g = tid & 15;
        s_att[tid] = s_red[     h]*s_red[48+     g]
                   + s_red[16 + h]*s_red[48+16 + g]
                   + s_red[32 + h]*s_red[48+32 + g];
    }
    __syncthreads();

    {
        int h = tid & 15, seg = tid >> 4;
        const float* w3 = W3 + h*256 + seg*16;
        const float* a  = s_att + seg*16;
        float p = 0.f;
        #pragma unroll
        for (int k = 0; k < 16; ++k) p = fmaf(a[k], w3[k], p);
        s_z[seg][h] = p;
    }
    __syncthreads();

    if (tid < 16) {
        float z = b3[tid];
        #pragma unroll
        for (int seg = 0; seg < 16; ++seg) z += s_z[seg][tid];
        s_a1[tid] = z / (1.0f + __expf(-z));
    }
    __syncthreads();

    if (tid == 0) {
        float accv = b4[0];
        #pragma unroll
        for (int cc = 0; cc < 16; ++cc) accv = fmaf(s_a1[cc], W4[cc], accv);
        out[i] = accv;
    }
}

extern "C" void kernel_launch(void* const* d_in, const int* in_sizes, int n_in,
                              void* d_out, int out_size, void* d_ws, size_t ws_size,
                              hipStream_t stream) {
    (void)in_sizes; (void)n_in; (void)out_size; (void)ws_size;
    const float* x  = (const float*)d_in[0];
    const float* W  = (const float*)d_in[1];
    const float* W1 = (const float*)d_in[2];
    const float* b1 = (const float*)d_in[3];
    const float* W2 = (const float*)d_in[4];
    const float* W3 = (const float*)d_in[5];
    const float* b3 = (const float*)d_in[6];
    const float* W4 = (const float*)d_in[7];
    const float* b4 = (const float*)d_in[8];

    float* att2t = (float*)d_ws;             // 512*1024
    float* part1 = att2t + 512*1024;         // 512*768
    float* part2 = part1 + 512*768;          // 512*1152
    float* Wt    = part2 + 512*1152;         // 2*512*256
    float* out   = (float*)d_out;

    k0 <<<1024, 256, 0, stream>>>(W, Wt);
    k1a<<<1024, 256, 0, stream>>>(x, Wt, part1);
    k1b<<< 512, 256, 0, stream>>>(part1, W1, b1, W2, att2t);
    k2a<<<1024, 256, 0, stream>>>(x, att2t, part2);
    k2b<<< 512, 256, 0, stream>>>(att2t, part2, W3, b3, W4, b4, out);
}

// Round 12
// 119.596 us; speedup vs baseline: 1.2588x; 1.2588x over previous
//
#include <hip/hip_runtime.h>
#include <hip/hip_bf16.h>
#include <math.h>

#define NN 512

// smearing constants
#define START 0.006737946999085467f            // exp(-5)
#define STEP  ((1.0f - START) * (1.0f/15.0f))  // linspace step
#define SB    (0.125f * (1.0f - START))
#define BETA  (1.0f/(SB*SB))
#define LOG2E 1.4426950408889634f
#define NB    (-(BETA)*LOG2E)                  // exp(-beta t^2) = exp2(NB t^2)

// ===========================================================================
// R12 = exact R10 revert (best measured: 119.3 us).
// R11 lesson (third register-schedule failure mode): acc[72] + 16 staged
// float4 -> allocator picks a 72-VGPR schedule and SERIALIZES the staged
// loads (VALUBusy 16%). Law: acc + staged in-flight must stay <= ~140 live;
// R10's acc[24|36] + 32 staged ~ 110 is the sweet spot.
//  - NO __launch_bounds__ min-wave hint (R9: clamp -> 210 MB scratch spill).
//  - t-loop unroll 1: one tile's 8 float4 in flight.
//  - fp32 G in LDS (row stride 64B -> 2-way bank aliasing, free).
//  - k0 W-transpose + transposed att2t: contract loads are float4.
// Grid 1024 = 128 i-tiles(x4) x 8 j-chunks(x64). 256 thr = 16c x 16js.
// ===========================================================================

__global__ __launch_bounds__(256) void k0(const float* __restrict__ W,
                                          float* __restrict__ Wt)
{
    __shared__ float ldsb[256];
    const int row = blockIdx.x;                // (a,j) 0..1023
    ldsb[threadIdx.x] = W[(size_t)row*256 + threadIdx.x];
    __syncthreads();
    const int c = threadIdx.x >> 4, r = threadIdx.x & 15;
    Wt[(size_t)row*256 + threadIdx.x] = ldsb[r*16 + c];   // Wt[row][c][r]
}

// ---------------------------------------------------------------------------
// k1a: stage-1 partials. part1[i][jc][96], 96 = kq*48 + b*16 + c.
// ---------------------------------------------------------------------------
__global__ __launch_bounds__(256) void k1a(const float* __restrict__ x,
                                           const float* __restrict__ Wt,
                                           float* __restrict__ part1)
{
    const int ib = blockIdx.x & 127, jc = blockIdx.x >> 7;
    const int i0 = ib * 4;
    const int tid = threadIdx.x;
    const int c = tid & 15, js = tid >> 4;
    const int lane = tid & 63, wv = tid >> 6;

    __shared__ float  lG[4][64][16];           // fp32 G
    __shared__ float4 lP[4][64];
    __shared__ float  s_part[4][16][26];

    // ---- phase 1: G + d for all (4 i) x (64 j), one (i,j) per thread ----
    {
        const int pi = tid >> 6, pj = tid & 63;
        const int jg = jc*64 + pj;
        const float xi0 = x[(i0+pi)*3+0], xi1 = x[(i0+pi)*3+1], xi2 = x[(i0+pi)*3+2];
        float d0 = xi0 - x[jg*3+0];
        float d1 = xi1 - x[jg*3+1];
        float d2 = xi2 - x[jg*3+2];
        float nsq = fmaf(d0,d0, fmaf(d1,d1, fmaf(d2,d2, 1e-6f)));
        float rs  = __builtin_amdgcn_rsqf(nsq);
        float nrm = nsq * rs;
        float inv = rs * rs;
        float cutv = 0.f;
        if (nrm < 5.0f) cutv = 0.5f*(__cosf(nrm*0.6283185307179586f)+1.0f);
        float en = exp2f(-LOG2E * nrm);
        lP[pi][pj] = make_float4(d0*inv, d1*inv, d2*inv, 0.f);
        float4* dst = reinterpret_cast<float4*>(&lG[pi][pj][0]);
        #pragma unroll
        for (int rq = 0; rq < 4; ++rq) {
            float t0 = en - (START + STEP*(float)(4*rq+0));
            float t1 = en - (START + STEP*(float)(4*rq+1));
            float t2 = en - (START + STEP*(float)(4*rq+2));
            float t3 = en - (START + STEP*(float)(4*rq+3));
            dst[rq] = make_float4(cutv*exp2f(NB*t0*t0), cutv*exp2f(NB*t1*t1),
                                  cutv*exp2f(NB*t2*t2), cutv*exp2f(NB*t3*t3));
        }
    }
    __syncthreads();                            // the ONLY main-loop barrier

    float acc[24];                              // i*6 + kq*3 + b
    #pragma unroll
    for (int v = 0; v < 24; ++v) acc[v] = 0.f;

    #pragma unroll 1
    for (int t = 0; t < 4; ++t) {
        const int jl = js + 16*t;
        const int jg = jc*64 + jl;
        const float4* Kp = reinterpret_cast<const float4*>(Wt + (size_t)jg*256 + c*16);
        const float4* Qp = reinterpret_cast<const float4*>(Wt + (size_t)NN*256 + (size_t)jg*256 + c*16);
        float4 ka = Kp[0], kb = Kp[1], kc = Kp[2], kd = Kp[3];
        float4 qa = Qp[0], qb = Qp[1], qc = Qp[2], qd = Qp[3];

        #pragma unroll
        for (int i = 0; i < 4; ++i) {
            const float4* gp = reinterpret_cast<const float4*>(&lG[i][jl][0]);
            float4 g0 = gp[0], g1 = gp[1], g2 = gp[2], g3 = gp[3];
            float tk, tq;
            tk = g0.x*ka.x; tq = g0.x*qa.x;
            tk = fmaf(g0.y,ka.y,tk); tq = fmaf(g0.y,qa.y,tq);
            tk = fmaf(g0.z,ka.z,tk); tq = fmaf(g0.z,qa.z,tq);
            tk = fmaf(g0.w,ka.w,tk); tq = fmaf(g0.w,qa.w,tq);
            tk = fmaf(g1.x,kb.x,tk); tq = fmaf(g1.x,qb.x,tq);
            tk = fmaf(g1.y,kb.y,tk); tq = fmaf(g1.y,qb.y,tq);
            tk = fmaf(g1.z,kb.z,tk); tq = fmaf(g1.z,qb.z,tq);
            tk = fmaf(g1.w,kb.w,tk); tq = fmaf(g1.w,qb.w,tq);
            tk = fmaf(g2.x,kc.x,tk); tq = fmaf(g2.x,qc.x,tq);
            tk = fmaf(g2.y,kc.y,tk); tq = fmaf(g2.y,qc.y,tq);
            tk = fmaf(g2.z,kc.z,tk); tq = fmaf(g2.z,qc.z,tq);
            tk = fmaf(g2.w,kc.w,tk); tq = fmaf(g2.w,qc.w,tq);
            tk = fmaf(g3.x,kd.x,tk); tq = fmaf(g3.x,qd.x,tq);
            tk = fmaf(g3.y,kd.y,tk); tq = fmaf(g3.y,qd.y,tq);
            tk = fmaf(g3.z,kd.z,tk); tq = fmaf(g3.z,qd.z,tq);
            tk = fmaf(g3.w,kd.w,tk); tq = fmaf(g3.w,qd.w,tq);
            float4 dd = lP[i][jl];
            acc[i*6+0] = fmaf(tk, dd.x, acc[i*6+0]);
            acc[i*6+1] = fmaf(tk, dd.y, acc[i*6+1]);
            acc[i*6+2] = fmaf(tk, dd.z, acc[i*6+2]);
            acc[i*6+3] = fmaf(tq, dd.x, acc[i*6+3]);
            acc[i*6+4] = fmaf(tq, dd.y, acc[i*6+4]);
            acc[i*6+5] = fmaf(tq, dd.z, acc[i*6+5]);
        }
    }

    #pragma unroll
    for (int v = 0; v < 24; ++v) {
        float t = acc[v];
        t += __shfl_xor(t, 16);
        t += __shfl_xor(t, 32);
        if (lane < 16) s_part[wv][c][v] = t;
    }
    __syncthreads();

    for (int v = tid; v < 384; v += 256) {
        int i = v / 96, o = v - i*96;
        int kq = o / 48, rem = o - kq*48;
        int b = rem >> 4, c2 = rem & 15;
        int f = i*6 + kq*3 + b;
        float sum = s_part[0][c2][f] + s_part[1][c2][f]
                  + s_part[2][c2][f] + s_part[3][c2][f];
        part1[(i0+i)*768 + jc*96 + o] = sum;
    }
}

// ---------------------------------------------------------------------------
// k1b: reduce 8 partials -> att1 -> silu(W1) -> att2 row (TRANSPOSED store).
// att2t[i][q2][c][r] = att2[i][q2*256 + r*16 + c]
// ---------------------------------------------------------------------------
__global__ __launch_bounds__(256) void k1b(const float* __restrict__ part1,
                                           const float* __restrict__ W1,
                                           const float* __restrict__ b1,
                                           const float* __restrict__ W2,
                                           float* __restrict__ att2t)
{
    const int i = blockIdx.x;
    const int tid = threadIdx.x;
    __shared__ float s_bkq[96];
    __shared__ float s_att[256];
    __shared__ float s_z[16][16];
    __shared__ float s_a1[16];

    if (tid < 96) {
        const float* p = part1 + i*768 + tid;
        float s = 0.f;
        #pragma unroll
        for (int k = 0; k < 8; ++k) s += p[k*96];
        s_bkq[tid] = s;
    }
    __syncthreads();

    {
        int h = tid >> 4, g = tid & 15;
        s_att[tid] = s_bkq[     h]*s_bkq[48+     g]
                   + s_bkq[16 + h]*s_bkq[48+16 + g]
                   + s_bkq[32 + h]*s_bkq[48+32 + g];
    }
    __syncthreads();

    {
        int h = tid & 15, seg = tid >> 4;
        const float* w1 = W1 + h*256 + seg*16;
        const float* a  = s_att + seg*16;
        float p = 0.f;
        #pragma unroll
        for (int k = 0; k < 16; ++k) p = fmaf(a[k], w1[k], p);
        s_z[seg][h] = p;
    }
    __syncthreads();

    if (tid < 16) {
        float z = b1[tid];
        #pragma unroll
        for (int seg = 0; seg < 16; ++seg) z += s_z[seg][tid];
        s_a1[tid] = z / (1.0f + __expf(-z));
    }
    __syncthreads();

    float a1[16];
    #pragma unroll
    for (int cc = 0; cc < 16; ++cc) a1[cc] = s_a1[cc];
    #pragma unroll
    for (int p = 0; p < 4; ++p) {
        int o = tid + p*256;
        const float4* w2 = reinterpret_cast<const float4*>(W2 + o*16);
        float4 wa = w2[0], wb = w2[1], wc = w2[2], wd = w2[3];
        float accv = wa.x*a1[0] + wa.y*a1[1] + wa.z*a1[2] + wa.w*a1[3]
                   + wb.x*a1[4] + wb.y*a1[5] + wb.z*a1[6] + wb.w*a1[7]
                   + wc.x*a1[8] + wc.y*a1[9] + wc.z*a1[10]+ wc.w*a1[11]
                   + wd.x*a1[12]+ wd.y*a1[13]+ wd.z*a1[14]+ wd.w*a1[15];
        // transposed store: q2 = o>>8, r = (o>>4)&15, c = o&15
        att2t[i*1024 + ((o>>8)*256) + ((o&15)*16) + ((o>>4)&15)] = accv;
    }
}

// ---------------------------------------------------------------------------
// k2a: stage-3 right-term + S partials. part2[i][jc][144].
// ---------------------------------------------------------------------------
__global__ __launch_bounds__(256) void k2a(const float* __restrict__ x,
                                           const float* __restrict__ att2t,
                                           float* __restrict__ part2)
{
    const int ib = blockIdx.x & 127, jc = blockIdx.x >> 7;
    const int i0 = ib * 4;
    const int tid = threadIdx.x;
    const int c = tid & 15, js = tid >> 4;
    const int lane = tid & 63, wv = tid >> 6;

    __shared__ float  lG[4][64][16];
    __shared__ float4 lP[4][64];
    __shared__ float  s_part[4][16][38];

    {
        const int pi = tid >> 6, pj = tid & 63;
        const int jg = jc*64 + pj;
        const float xi0 = x[(i0+pi)*3+0], xi1 = x[(i0+pi)*3+1], xi2 = x[(i0+pi)*3+2];
        float d0 = xi0 - x[jg*3+0];
        float d1 = xi1 - x[jg*3+1];
        float d2 = xi2 - x[jg*3+2];
        float nsq = fmaf(d0,d0, fmaf(d1,d1, fmaf(d2,d2, 1e-6f)));
        float rs  = __builtin_amdgcn_rsqf(nsq);
        float nrm = nsq * rs;
        float inv = rs * rs;
        float cutv = 0.f;
        if (nrm < 5.0f) cutv = 0.5f*(__cosf(nrm*0.6283185307179586f)+1.0f);
        float en = exp2f(-LOG2E * nrm);
        lP[pi][pj] = make_float4(d0*inv, d1*inv, d2*inv, 0.f);
        float4* dst = reinterpret_cast<float4*>(&lG[pi][pj][0]);
        #pragma unroll
        for (int rq = 0; rq < 4; ++rq) {
            float t0 = en - (START + STEP*(float)(4*rq+0));
            float t1 = en - (START + STEP*(float)(4*rq+1));
            float t2 = en - (START + STEP*(float)(4*rq+2));
            float t3 = en - (START + STEP*(float)(4*rq+3));
            dst[rq] = make_float4(cutv*exp2f(NB*t0*t0), cutv*exp2f(NB*t1*t1),
                                  cutv*exp2f(NB*t2*t2), cutv*exp2f(NB*t3*t3));
        }
    }
    __syncthreads();

    float acc[36];                              // 24 main + 12 S (24+i*3+b, r=c)
    #pragma unroll
    for (int v = 0; v < 36; ++v) acc[v] = 0.f;

    #pragma unroll 1
    for (int t = 0; t < 4; ++t) {
        const int jl = js + 16*t;
        const int jg = jc*64 + jl;
        const float4* Kp = reinterpret_cast<const float4*>(att2t + (size_t)jg*1024 + 512 + c*16);
        const float4* Qp = reinterpret_cast<const float4*>(att2t + (size_t)jg*1024 + 768 + c*16);
        float4 ka = Kp[0], kb = Kp[1], kc = Kp[2], kd = Kp[3];
        float4 qa = Qp[0], qb = Qp[1], qc = Qp[2], qd = Qp[3];

        #pragma unroll
        for (int i = 0; i < 4; ++i) {
            const float4* gp = reinterpret_cast<const float4*>(&lG[i][jl][0]);
            float4 g0 = gp[0], g1 = gp[1], g2 = gp[2], g3 = gp[3];
            float tk, tq;
            tk = g0.x*ka.x; tq = g0.x*qa.x;
            tk = fmaf(g0.y,ka.y,tk); tq = fmaf(g0.y,qa.y,tq);
            tk = fmaf(g0.z,ka.z,tk); tq = fmaf(g0.z,qa.z,tq);
            tk = fmaf(g0.w,ka.w,tk); tq = fmaf(g0.w,qa.w,tq);
            tk = fmaf(g1.x,kb.x,tk); tq = fmaf(g1.x,qb.x,tq);
            tk = fmaf(g1.y,kb.y,tk); tq = fmaf(g1.y,qb.y,tq);
            tk = fmaf(g1.z,kb.z,tk); tq = fmaf(g1.z,qb.z,tq);
            tk = fmaf(g1.w,kb.w,tk); tq = fmaf(g1.w,qb.w,tq);
            tk = fmaf(g2.x,kc.x,tk); tq = fmaf(g2.x,qc.x,tq);
            tk = fmaf(g2.y,kc.y,tk); tq = fmaf(g2.y,qc.y,tq);
            tk = fmaf(g2.z,kc.z,tk); tq = fmaf(g2.z,qc.z,tq);
            tk = fmaf(g2.w,kc.w,tk); tq = fmaf(g2.w,qc.w,tq);
            tk = fmaf(g3.x,kd.x,tk); tq = fmaf(g3.x,qd.x,tq);
            tk = fmaf(g3.y,kd.y,tk); tq = fmaf(g3.y,qd.y,tq);
            tk = fmaf(g3.z,kd.z,tk); tq = fmaf(g3.z,qd.z,tq);
            tk = fmaf(g3.w,kd.w,tk); tq = fmaf(g3.w,qd.w,tq);
            float4 dd = lP[i][jl];
            acc[i*6+0] = fmaf(tk, dd.x, acc[i*6+0]);
            acc[i*6+1] = fmaf(tk, dd.y, acc[i*6+1]);
            acc[i*6+2] = fmaf(tk, dd.z, acc[i*6+2]);
            acc[i*6+3] = fmaf(tq, dd.x, acc[i*6+3]);
            acc[i*6+4] = fmaf(tq, dd.y, acc[i*6+4]);
            acc[i*6+5] = fmaf(tq, dd.z, acc[i*6+5]);
            float gc = lG[i][jl][c];            // this lane's r=c for S
            acc[24+i*3+0] = fmaf(gc, dd.x, acc[24+i*3+0]);
            acc[24+i*3+1] = fmaf(gc, dd.y, acc[24+i*3+1]);
            acc[24+i*3+2] = fmaf(gc, dd.z, acc[24+i*3+2]);
        }
    }

    #pragma unroll
    for (int v = 0; v < 36; ++v) {
        float t = acc[v];
        t += __shfl_xor(t, 16);
        t += __shfl_xor(t, 32);
        if (lane < 16) s_part[wv][c][v] = t;
    }
    __syncthreads();

    for (int v = tid; v < 576; v += 256) {
        int i = v / 144, o = v - i*144;
        int c2, f;
        if (o < 96) {
            int kq = o / 48, rem = o - kq*48;
            int b = rem >> 4; c2 = rem & 15;
            f = i*6 + kq*3 + b;
        } else {
            int oS = o - 96;
            int r = oS / 3, b = oS - r*3;
            c2 = r;
            f = 24 + i*3 + b;
        }
        float sum = s_part[0][c2][f] + s_part[1][c2][f]
                  + s_part[2][c2][f] + s_part[3][c2][f];
        part2[(i0+i)*1152 + jc*144 + o] = sum;
    }
}

// ---------------------------------------------------------------------------
// k2b: reduce 8 partials + left-term (transposed att2t rows) -> out. Grid 512.
// ---------------------------------------------------------------------------
__global__ __launch_bounds__(256) void k2b(const float* __restrict__ att2t,
                                           const float* __restrict__ part2,
                                           const float* __restrict__ W3,
                                           const float* __restrict__ b3,
                                           const float* __restrict__ W4,
                                           const float* __restrict__ b4,
                                           float* __restrict__ out)
{
    const int i = blockIdx.x;
    const int tid = threadIdx.x;
    __shared__ float s_red[144];
    __shared__ float s_att[256];
    __shared__ float s_z[16][16];
    __shared__ float s_a1[16];

    if (tid < 144) {
        const float* p = part2 + i*1152 + tid;
        float s = 0.f;
        #pragma unroll
        for (int k = 0; k < 8; ++k) s += p[k*144];
        s_red[tid] = s;
    }
    __syncthreads();

    if (tid < 96) {                      // left-term: bkq[c,b] += sum_r left[r,c]*S[r,b]
        int kq = tid / 48, rem = tid - kq*48;
        int b = rem >> 4, cc = rem & 15;
        const float4* lrow = reinterpret_cast<const float4*>(att2t + i*1024 + kq*256 + cc*16);
        float4 A = lrow[0], B = lrow[1], C = lrow[2], D = lrow[3];
        float add = 0.f;
        add = fmaf(A.x, s_red[96+ 0*3+b], add);
        add = fmaf(A.y, s_red[96+ 1*3+b], add);
        add = fmaf(A.z, s_red[96+ 2*3+b], add);
        add = fmaf(A.w, s_red[96+ 3*3+b], add);
        add = fmaf(B.x, s_red[96+ 4*3+b], add);
        add = fmaf(B.y, s_red[96+ 5*3+b], add);
        add = fmaf(B.z, s_red[96+ 6*3+b], add);
        add = fmaf(B.w, s_red[96+ 7*3+b], add);
        add = fmaf(C.x, s_red[96+ 8*3+b], add);
        add = fmaf(C.y, s_red[96+ 9*3+b], add);
        add = fmaf(C.z, s_red[96+10*3+b], add);
        add = fmaf(C.w, s_red[96+11*3+b], add);
        add = fmaf(D.x, s_red[96+12*3+b], add);
        add = fmaf(D.y, s_red[96+13*3+b], add);
        add = fmaf(D.z, s_red[96+14*3+b], add);
        add = fmaf(D.w, s_red[96+15*3+b], add);
        s_red[tid] += add;
    }
    __syncthreads();

    {
        int h = tid >> 4, g = tid & 15;
        s_att[tid] = s_red[     h]*s_red[48+     g]
                   + s_red[16 + h]*s_red[48+16 + g]
                   + s_red[32 + h]*s_red[48+32 + g];
    }
    __syncthreads();

    {
        int h = tid & 15, seg = tid >> 4;
        const float* w3 = W3 + h*256 + seg*16;
        const float* a  = s_att + seg*16;
        float p = 0.f;
        #pragma unroll
        for (int k = 0; k < 16; ++k) p = fmaf(a[k], w3[k], p);
        s_z[seg][h] = p;
    }
    __syncthreads();

    if (tid < 16) {
        float z = b3[tid];
        #pragma unroll
        for (int seg = 0; seg < 16; ++seg) z += s_z[seg][tid];
        s_a1[tid] = z / (1.0f + __expf(-z));
    }
    __syncthreads();

    if (tid == 0) {
        float accv = b4[0];
        #pragma unroll
        for (int cc = 0; cc < 16; ++cc) accv = fmaf(s_a1[cc], W4[cc], accv);
        out[i] = accv;
    }
}

extern "C" void kernel_launch(void* const* d_in, const int* in_sizes, int n_in,
                              void* d_out, int out_size, void* d_ws, size_t ws_size,
                              hipStream_t stream) {
    (void)in_sizes; (void)n_in; (void)out_size; (void)ws_size;
    const float* x  = (const float*)d_in[0];
    const float* W  = (const float*)d_in[1];
    const float* W1 = (const float*)d_in[2];
    const float* b1 = (const float*)d_in[3];
    const float* W2 = (const float*)d_in[4];
    const float* W3 = (const float*)d_in[5];
    const float* b3 = (const float*)d_in[6];
    const float* W4 = (const float*)d_in[7];
    const float* b4 = (const float*)d_in[8];

    float* att2t = (float*)d_ws;             // 512*1024
    float* part1 = att2t + 512*1024;         // 512*768
    float* part2 = part1 + 512*768;          // 512*1152
    float* Wt    = part2 + 512*1152;         // 2*512*256
    float* out   = (float*)d_out;

    k0 <<<1024, 256, 0, stream>>>(W, Wt);
    k1a<<<1024, 256, 0, stream>>>(x, Wt, part1);
    k1b<<< 512, 256, 0, stream>>>(part1, W1, b1, W2, att2t);
    k2a<<<1024, 256, 0, stream>>>(x, att2t, part2);
    k2b<<< 512, 256, 0, stream>>>(att2t, part2, W3, b3, W4, b4, out);
}